// Round 1
// baseline (296.792 us; speedup 1.0000x reference)
//
#include <hip/hip_runtime.h>
#include <hip/hip_bf16.h>
#include <math.h>

typedef __hip_bfloat16 bf16;
typedef __attribute__((ext_vector_type(8))) short short8;
typedef __attribute__((ext_vector_type(4))) float f32x4;

#define NB 2
#define NS 2048
#define ND 1024
#define NH 16
#define NHD 64
#define N3D 3072

// ---------------- fp32 -> bf16 cast (4-wide) ----------------
__global__ void cast_kernel(const float4* __restrict__ in, bf16* __restrict__ out, int n4) {
  int i = blockIdx.x * blockDim.x + threadIdx.x;
  if (i >= n4) return;
  float4 v = in[i];
  alignas(8) bf16 r[4];
  r[0] = __float2bfloat16(v.x);
  r[1] = __float2bfloat16(v.y);
  r[2] = __float2bfloat16(v.z);
  r[3] = __float2bfloat16(v.w);
  *reinterpret_cast<uint2*>(out + (size_t)i * 4) = *reinterpret_cast<const uint2*>(r);
}

// ---------------- bf16 GEMM: C[M,N] = A[M,K] * B[N,K]^T ----------------
// 64x64 tile, 4 waves (each 32x32), BK=64, padded LDS (+8 shorts -> 2-way conflict, free).
template <bool OUT_BF16>
__global__ __launch_bounds__(256) void gemm_bt(const bf16* __restrict__ A,
                                               const bf16* __restrict__ Bm,
                                               void* __restrict__ Cv,
                                               int M, int N, int K) {
  __shared__ short As[64][72];
  __shared__ short Bs[64][72];
  const int tid = threadIdx.x;
  const int lane = tid & 63;
  const int wid = tid >> 6;
  const int wr = wid >> 1, wc = wid & 1;
  const int l15 = lane & 15, l4 = lane >> 4;
  const int bn0 = blockIdx.x * 64, bm0 = blockIdx.y * 64;
  f32x4 acc[2][2] = {};
  for (int k0 = 0; k0 < K; k0 += 64) {
    __syncthreads();
#pragma unroll
    for (int it = 0; it < 2; ++it) {
      int e = (it * 256 + tid) * 8;
      int r = e >> 6, c = e & 63;
      *reinterpret_cast<short8*>(&As[r][c]) =
          *reinterpret_cast<const short8*>(&A[(size_t)(bm0 + r) * K + k0 + c]);
      *reinterpret_cast<short8*>(&Bs[r][c]) =
          *reinterpret_cast<const short8*>(&Bm[(size_t)(bn0 + r) * K + k0 + c]);
    }
    __syncthreads();
#pragma unroll
    for (int kk = 0; kk < 64; kk += 32) {
      short8 af[2], bfr[2];
#pragma unroll
      for (int t = 0; t < 2; ++t) {
        af[t] = *reinterpret_cast<const short8*>(&As[wr * 32 + t * 16 + l15][kk + l4 * 8]);
        bfr[t] = *reinterpret_cast<const short8*>(&Bs[wc * 32 + t * 16 + l15][kk + l4 * 8]);
      }
#pragma unroll
      for (int rt = 0; rt < 2; ++rt)
#pragma unroll
        for (int ct = 0; ct < 2; ++ct)
          acc[rt][ct] = __builtin_amdgcn_mfma_f32_16x16x32_bf16(af[rt], bfr[ct], acc[rt][ct], 0, 0, 0);
    }
  }
  // C/D layout: col = lane&15, row = (lane>>4)*4 + r   [m89-verified]
#pragma unroll
  for (int rt = 0; rt < 2; ++rt)
#pragma unroll
    for (int ct = 0; ct < 2; ++ct)
#pragma unroll
      for (int r = 0; r < 4; ++r) {
        int row = bm0 + wr * 32 + rt * 16 + l4 * 4 + r;
        int col = bn0 + wc * 32 + ct * 16 + l15;
        if (OUT_BF16)
          reinterpret_cast<bf16*>(Cv)[(size_t)row * N + col] = __float2bfloat16(acc[rt][ct][r]);
        else
          reinterpret_cast<float*>(Cv)[(size_t)row * N + col] = acc[rt][ct][r];
      }
}

// ---------------- RoPE: qkv(bf16 [B,S,3,H,HD]) -> Qr,Kr (bf16 [B,H,S,HD]) ----------------
__global__ void rope_kernel(const bf16* __restrict__ qkv, bf16* __restrict__ Qr,
                            bf16* __restrict__ Kr) {
  int idx = blockIdx.x * blockDim.x + threadIdx.x;  // 2^21 total: b[1] h[4] s[11] j[5]
  int j = idx & 31;
  int s = (idx >> 5) & (NS - 1);
  int h = (idx >> 16) & (NH - 1);
  int b = idx >> 20;
  size_t base = (size_t)(b * NS + s) * N3D + h * NHD;
  float q0 = __bfloat162float(qkv[base + j]);
  float q1 = __bfloat162float(qkv[base + j + 32]);
  float k0 = __bfloat162float(qkv[base + ND + j]);
  float k1 = __bfloat162float(qkv[base + ND + j + 32]);
  // inv_freq = 10000^(-2j/64) ; log2(10000) = 13.287712379549449
  float inv = exp2f((float)(2 * j) * (-13.287712379549449f / 64.0f));
  float ang = (float)s * inv;
  float sn, cs;
  sincosf(ang, &sn, &cs);
  size_t o = ((size_t)(b * NH + h) * NS + s) * NHD + j;
  Qr[o] = __float2bfloat16(q0 * cs - q1 * sn);
  Qr[o + 32] = __float2bfloat16(q1 * cs + q0 * sn);
  Kr[o] = __float2bfloat16(k0 * cs - k1 * sn);
  Kr[o + 32] = __float2bfloat16(k1 * cs + k0 * sn);
}

// ---------------- V transpose: qkv v-part -> Vt (bf16 [B,H,HD,S]) ----------------
__global__ __launch_bounds__(256) void vtrans_kernel(const bf16* __restrict__ qkv,
                                                     bf16* __restrict__ Vt) {
  int bh = blockIdx.y;
  int b = bh >> 4, h = bh & 15;
  int s0 = blockIdx.x * 64;
  __shared__ bf16 tile[64][72];
#pragma unroll
  for (int it = 0; it < 16; ++it) {
    int e = it * 256 + threadIdx.x;
    int sr = e >> 6, hd = e & 63;
    tile[sr][hd] = qkv[(size_t)(b * NS + s0 + sr) * N3D + 2 * ND + h * NHD + hd];
  }
  __syncthreads();
#pragma unroll
  for (int it = 0; it < 16; ++it) {
    int e = it * 256 + threadIdx.x;
    int hd = e >> 6, sc = e & 63;
    Vt[((size_t)bh * NHD + hd) * NS + s0 + sc] = tile[sc][hd];
  }
}

// ---------------- causal flash attention ----------------
// 1 wave/block, 32 q-rows/wave, KV chunk 64. Qr,Kr: [B,H,S,HD]; Vt: [B,H,HD,S].
__global__ __launch_bounds__(64) void attn_kernel(const bf16* __restrict__ Qr,
                                                  const bf16* __restrict__ Kr,
                                                  const bf16* __restrict__ Vt,
                                                  const int* __restrict__ amask,
                                                  bf16* __restrict__ AO) {
  const int lane = threadIdx.x;
  const int l15 = lane & 15, l4 = lane >> 4;
  const int bh = blockIdx.y, b = bh >> 4, h = bh & 15;
  const int q0 = blockIdx.x * 32;
  __shared__ short Pl[2][16][72];  // P tiles for acc->A-frag transpose (pad 8 -> 2-way)

  const bf16* Qb = Qr + (size_t)bh * NS * NHD;
  const bf16* Kb = Kr + (size_t)bh * NS * NHD;
  const bf16* Vb = Vt + (size_t)bh * NHD * NS;

  // Q fragments: A[row=q(l15)][k=hd=(l>>4)*8+j], kk walks hd 0..31 / 32..63
  short8 aq[2][2];
#pragma unroll
  for (int rt = 0; rt < 2; ++rt)
#pragma unroll
    for (int kk = 0; kk < 2; ++kk)
      aq[rt][kk] = *reinterpret_cast<const short8*>(
          &Qb[(size_t)(q0 + rt * 16 + l15) * NHD + kk * 32 + l4 * 8]);

  float m[2][4], lsum[2][4];
  f32x4 o[2][4] = {};
#pragma unroll
  for (int rt = 0; rt < 2; ++rt)
#pragma unroll
    for (int r = 0; r < 4; ++r) {
      m[rt][r] = -1e30f;
      lsum[rt][r] = 0.f;
    }

  const int nchunk = q0 / 64 + 1;  // chunks cover kv in [0, q0+32)
  for (int c = 0; c < nchunk; ++c) {
    const int kv0 = c * 64;
    // K fragments: B[k=hd][col=kv(l15)] -> read K[kv][hd], 16B contiguous
    short8 bk[4][2];
#pragma unroll
    for (int ct = 0; ct < 4; ++ct)
#pragma unroll
      for (int kk = 0; kk < 2; ++kk)
        bk[ct][kk] = *reinterpret_cast<const short8*>(
            &Kb[(size_t)(kv0 + ct * 16 + l15) * NHD + kk * 32 + l4 * 8]);
    bool mok[4];
#pragma unroll
    for (int ct = 0; ct < 4; ++ct) mok[ct] = amask[b * NS + kv0 + ct * 16 + l15] != 0;

    f32x4 sc[2][4];
#pragma unroll
    for (int rt = 0; rt < 2; ++rt)
#pragma unroll
      for (int ct = 0; ct < 4; ++ct) {
        f32x4 z = {};
        z = __builtin_amdgcn_mfma_f32_16x16x32_bf16(aq[rt][0], bk[ct][0], z, 0, 0, 0);
        sc[rt][ct] = __builtin_amdgcn_mfma_f32_16x16x32_bf16(aq[rt][1], bk[ct][1], z, 0, 0, 0);
      }

#pragma unroll
    for (int rt = 0; rt < 2; ++rt) {
      // scale + causal + padding mask
#pragma unroll
      for (int ct = 0; ct < 4; ++ct) {
        int col = kv0 + ct * 16 + l15;
#pragma unroll
        for (int r = 0; r < 4; ++r) {
          int row = q0 + rt * 16 + l4 * 4 + r;
          float v = sc[rt][ct][r] * 0.125f;
          if (col > row || !mok[ct]) v = -1e30f;
          sc[rt][ct][r] = v;
        }
      }
      // online softmax (rows live in 16-lane groups; reduce via shfl_xor 1,2,4,8)
      float pm[4], fac[4];
#pragma unroll
      for (int r = 0; r < 4; ++r) {
        float v = fmaxf(fmaxf(sc[rt][0][r], sc[rt][1][r]), fmaxf(sc[rt][2][r], sc[rt][3][r]));
        v = fmaxf(v, __shfl_xor(v, 1));
        v = fmaxf(v, __shfl_xor(v, 2));
        v = fmaxf(v, __shfl_xor(v, 4));
        v = fmaxf(v, __shfl_xor(v, 8));
        pm[r] = v;
      }
#pragma unroll
      for (int r = 0; r < 4; ++r) {
        float mn = fmaxf(m[rt][r], pm[r]);
        fac[r] = expf(m[rt][r] - mn);
        m[rt][r] = mn;
      }
      float rs[4] = {0.f, 0.f, 0.f, 0.f};
#pragma unroll
      for (int ct = 0; ct < 4; ++ct)
#pragma unroll
        for (int r = 0; r < 4; ++r) {
          float p = expf(sc[rt][ct][r] - m[rt][r]);
          sc[rt][ct][r] = p;
          rs[r] += p;
        }
#pragma unroll
      for (int r = 0; r < 4; ++r) {
        float v = rs[r];
        v += __shfl_xor(v, 1);
        v += __shfl_xor(v, 2);
        v += __shfl_xor(v, 4);
        v += __shfl_xor(v, 8);
        lsum[rt][r] = lsum[rt][r] * fac[r] + v;
      }
#pragma unroll
      for (int ht = 0; ht < 4; ++ht)
#pragma unroll
        for (int r = 0; r < 4; ++r) o[rt][ht][r] *= fac[r];
      // P (acc layout) -> LDS for A-frag reads
#pragma unroll
      for (int ct = 0; ct < 4; ++ct)
#pragma unroll
        for (int r = 0; r < 4; ++r) {
          bf16 hv = __float2bfloat16(sc[rt][ct][r]);
          Pl[rt][l4 * 4 + r][ct * 16 + l15] = *reinterpret_cast<short*>(&hv);
        }
    }
    __syncthreads();
    // PV: O[q][hd] += P[q][kv] * V[kv][hd]
#pragma unroll
    for (int rt = 0; rt < 2; ++rt) {
      short8 pa[2];
#pragma unroll
      for (int kh = 0; kh < 2; ++kh)
        pa[kh] = *reinterpret_cast<const short8*>(&Pl[rt][l15][kh * 32 + l4 * 8]);
#pragma unroll
      for (int ht = 0; ht < 4; ++ht)
#pragma unroll
        for (int kh = 0; kh < 2; ++kh) {
          short8 bv = *reinterpret_cast<const short8*>(
              &Vb[(size_t)(ht * 16 + l15) * NS + kv0 + kh * 32 + l4 * 8]);
          o[rt][ht] = __builtin_amdgcn_mfma_f32_16x16x32_bf16(pa[kh], bv, o[rt][ht], 0, 0, 0);
        }
    }
    __syncthreads();
  }
  // epilogue: normalize, write AO bf16 [B,S,D]
#pragma unroll
  for (int rt = 0; rt < 2; ++rt)
#pragma unroll
    for (int ht = 0; ht < 4; ++ht)
#pragma unroll
      for (int r = 0; r < 4; ++r) {
        int srow = q0 + rt * 16 + l4 * 4 + r;
        float val = o[rt][ht][r] / lsum[rt][r];
        AO[(size_t)(b * NS + srow) * ND + h * NHD + ht * 16 + l15] = __float2bfloat16(val);
      }
}

extern "C" void kernel_launch(void* const* d_in, const int* in_sizes, int n_in,
                              void* d_out, int out_size, void* d_ws, size_t ws_size,
                              hipStream_t stream) {
  const float* x = (const float*)d_in[0];
  const int* amask = (const int*)d_in[1];
  const float* Wqkv = (const float*)d_in[2];
  const float* Wout = (const float*)d_in[3];
  float* out = (float*)d_out;

  // workspace carve (64 MB total); AO aliases xb (xb dead after QKV GEMM)
  char* p = (char*)d_ws;
  bf16* xb = (bf16*)(p);                      // 8,388,608
  bf16* wqkvb = (bf16*)(p + 8388608);         // 6,291,456
  bf16* woutb = (bf16*)(p + 14680064);        // 2,097,152
  bf16* qkvb = (bf16*)(p + 16777216);         // 25,165,824
  bf16* Qr = (bf16*)(p + 41943040);           // 8,388,608
  bf16* Kr = (bf16*)(p + 50331648);           // 8,388,608
  bf16* Vt = (bf16*)(p + 58720256);           // 8,388,608 -> 67,108,864 end
  bf16* AO = xb;

  cast_kernel<<<4096, 256, 0, stream>>>((const float4*)x, xb, (NB * NS * ND) / 4);
  cast_kernel<<<3072, 256, 0, stream>>>((const float4*)Wqkv, wqkvb, (N3D * ND) / 4);
  cast_kernel<<<1024, 256, 0, stream>>>((const float4*)Wout, woutb, (ND * ND) / 4);

  // qkv = x @ Wqkv^T : [4096,3072]
  gemm_bt<true><<<dim3(N3D / 64, (NB * NS) / 64), 256, 0, stream>>>(xb, wqkvb, qkvb,
                                                                    NB * NS, N3D, ND);
  rope_kernel<<<(NB * NH * NS * 32) / 256, 256, 0, stream>>>(qkvb, Qr, Kr);
  vtrans_kernel<<<dim3(NS / 64, NB * NH), 256, 0, stream>>>(qkvb, Vt);
  attn_kernel<<<dim3(NS / 32, NB * NH), 64, 0, stream>>>(Qr, Kr, Vt, amask, AO);
  // out = AO @ Wout^T : [4096,1024] fp32
  gemm_bt<false><<<dim3(ND / 64, (NB * NS) / 64), 256, 0, stream>>>(AO, woutb, out,
                                                                    NB * NS, ND, ND);
}

// Round 2
// 240.850 us; speedup vs baseline: 1.2323x; 1.2323x over previous
//
#include <hip/hip_runtime.h>
#include <hip/hip_bf16.h>
#include <math.h>

typedef __hip_bfloat16 bf16;
typedef __attribute__((ext_vector_type(8))) short short8;
typedef __attribute__((ext_vector_type(4))) float f32x4;

#define NB 2
#define NS 2048
#define ND 1024
#define NH 16
#define NHD 64
#define N3D 3072

// scale folded into exp2 domain: (1/sqrt(64)) * log2(e)
#define SM_SCALE 0.18033688011112042f

// ---------------- fp32 -> bf16 cast (4-wide) ----------------
__global__ void cast_kernel(const float4* __restrict__ in, bf16* __restrict__ out, int n4) {
  int i = blockIdx.x * blockDim.x + threadIdx.x;
  if (i >= n4) return;
  float4 v = in[i];
  alignas(8) bf16 r[4];
  r[0] = __float2bfloat16(v.x);
  r[1] = __float2bfloat16(v.y);
  r[2] = __float2bfloat16(v.z);
  r[3] = __float2bfloat16(v.w);
  *reinterpret_cast<uint2*>(out + (size_t)i * 4) = *reinterpret_cast<const uint2*>(r);
}

// ---------------- bf16 GEMM: C[M,N] = A[M,K] * B[N,K]^T ----------------
template <bool OUT_BF16>
__global__ __launch_bounds__(256) void gemm_bt(const bf16* __restrict__ A,
                                               const bf16* __restrict__ Bm,
                                               void* __restrict__ Cv,
                                               int M, int N, int K) {
  __shared__ short As[64][72];
  __shared__ short Bs[64][72];
  const int tid = threadIdx.x;
  const int lane = tid & 63;
  const int wid = tid >> 6;
  const int wr = wid >> 1, wc = wid & 1;
  const int l15 = lane & 15, l4 = lane >> 4;
  const int bn0 = blockIdx.x * 64, bm0 = blockIdx.y * 64;
  f32x4 acc[2][2] = {};
  for (int k0 = 0; k0 < K; k0 += 64) {
    __syncthreads();
#pragma unroll
    for (int it = 0; it < 2; ++it) {
      int e = (it * 256 + tid) * 8;
      int r = e >> 6, c = e & 63;
      *reinterpret_cast<short8*>(&As[r][c]) =
          *reinterpret_cast<const short8*>(&A[(size_t)(bm0 + r) * K + k0 + c]);
      *reinterpret_cast<short8*>(&Bs[r][c]) =
          *reinterpret_cast<const short8*>(&Bm[(size_t)(bn0 + r) * K + k0 + c]);
    }
    __syncthreads();
#pragma unroll
    for (int kk = 0; kk < 64; kk += 32) {
      short8 af[2], bfr[2];
#pragma unroll
      for (int t = 0; t < 2; ++t) {
        af[t] = *reinterpret_cast<const short8*>(&As[wr * 32 + t * 16 + l15][kk + l4 * 8]);
        bfr[t] = *reinterpret_cast<const short8*>(&Bs[wc * 32 + t * 16 + l15][kk + l4 * 8]);
      }
#pragma unroll
      for (int rt = 0; rt < 2; ++rt)
#pragma unroll
        for (int ct = 0; ct < 2; ++ct)
          acc[rt][ct] = __builtin_amdgcn_mfma_f32_16x16x32_bf16(af[rt], bfr[ct], acc[rt][ct], 0, 0, 0);
    }
  }
#pragma unroll
  for (int rt = 0; rt < 2; ++rt)
#pragma unroll
    for (int ct = 0; ct < 2; ++ct)
#pragma unroll
      for (int r = 0; r < 4; ++r) {
        int row = bm0 + wr * 32 + rt * 16 + l4 * 4 + r;
        int col = bn0 + wc * 32 + ct * 16 + l15;
        if (OUT_BF16)
          reinterpret_cast<bf16*>(Cv)[(size_t)row * N + col] = __float2bfloat16(acc[rt][ct][r]);
        else
          reinterpret_cast<float*>(Cv)[(size_t)row * N + col] = acc[rt][ct][r];
      }
}

// ---------------- RoPE ----------------
__global__ void rope_kernel(const bf16* __restrict__ qkv, bf16* __restrict__ Qr,
                            bf16* __restrict__ Kr) {
  int idx = blockIdx.x * blockDim.x + threadIdx.x;
  int j = idx & 31;
  int s = (idx >> 5) & (NS - 1);
  int h = (idx >> 16) & (NH - 1);
  int b = idx >> 20;
  size_t base = (size_t)(b * NS + s) * N3D + h * NHD;
  float q0 = __bfloat162float(qkv[base + j]);
  float q1 = __bfloat162float(qkv[base + j + 32]);
  float k0 = __bfloat162float(qkv[base + ND + j]);
  float k1 = __bfloat162float(qkv[base + ND + j + 32]);
  float inv = exp2f((float)(2 * j) * (-13.287712379549449f / 64.0f));
  float ang = (float)s * inv;
  float sn, cs;
  sincosf(ang, &sn, &cs);
  size_t o = ((size_t)(b * NH + h) * NS + s) * NHD + j;
  Qr[o] = __float2bfloat16(q0 * cs - q1 * sn);
  Qr[o + 32] = __float2bfloat16(q1 * cs + q0 * sn);
  Kr[o] = __float2bfloat16(k0 * cs - k1 * sn);
  Kr[o + 32] = __float2bfloat16(k1 * cs + k0 * sn);
}

// ---------------- V transpose: qkv v-part -> Vt (bf16 [B,H,HD,S]) ----------------
__global__ __launch_bounds__(256) void vtrans_kernel(const bf16* __restrict__ qkv,
                                                     bf16* __restrict__ Vt) {
  int bh = blockIdx.y;
  int b = bh >> 4, h = bh & 15;
  int s0 = blockIdx.x * 64;
  __shared__ bf16 tile[64][72];
#pragma unroll
  for (int it = 0; it < 16; ++it) {
    int e = it * 256 + threadIdx.x;
    int sr = e >> 6, hd = e & 63;
    tile[sr][hd] = qkv[(size_t)(b * NS + s0 + sr) * N3D + 2 * ND + h * NHD + hd];
  }
  __syncthreads();
#pragma unroll
  for (int it = 0; it < 16; ++it) {
    int e = it * 256 + threadIdx.x;
    int hd = e >> 6, sc = e & 63;
    Vt[((size_t)bh * NHD + hd) * NS + s0 + sc] = tile[sc][hd];
  }
}

// ---------------- attn_mask -> float bias ----------------
__global__ void maskbias_kernel(const int* __restrict__ amask, float* __restrict__ mb, int n) {
  int i = blockIdx.x * blockDim.x + threadIdx.x;
  if (i < n) mb[i] = amask[i] ? 0.f : -1e30f;
}

// ---------------- causal flash attention: 4 waves/block, QBLK=128, KVBLK=64 ----------------
// K/V chunk double-buffered in LDS (T14 async-stage); softmax in exp2 domain.
__global__ __launch_bounds__(256, 2) void attn_kernel(const bf16* __restrict__ Qr,
                                                      const bf16* __restrict__ Kr,
                                                      const bf16* __restrict__ Vt,
                                                      const float* __restrict__ mb,
                                                      bf16* __restrict__ AO) {
  __shared__ short Ks[2][64][72];
  __shared__ short Vs[2][64][72];
  __shared__ float Mb[2][64];
  __shared__ short Pl[4][32][72];

  const int tid = threadIdx.x;
  const int lane = tid & 63;
  const int w = tid >> 6;
  const int l15 = lane & 15, l4 = lane >> 4;
  const int bh = blockIdx.y, b = bh >> 4;
  const int q0 = blockIdx.x * 128;
  const int qw = q0 + w * 32;

  const bf16* Qb = Qr + (size_t)bh * NS * NHD;
  const bf16* Kb = Kr + (size_t)bh * NS * NHD;
  const bf16* Vb = Vt + (size_t)bh * NHD * NS;

  // staging geometry: 256 threads x 8 shorts cover 32 rows x 64 cols per issue
  const int sr = (tid * 8) >> 6;
  const int scol = (tid * 8) & 63;

  // Q fragments in registers
  short8 aq[2][2];
#pragma unroll
  for (int qt = 0; qt < 2; ++qt)
#pragma unroll
    for (int kh = 0; kh < 2; ++kh)
      aq[qt][kh] = *reinterpret_cast<const short8*>(
          &Qb[(size_t)(qw + qt * 16 + l15) * NHD + kh * 32 + l4 * 8]);

  float m[2][4], lsum[2][4];
  f32x4 o[2][4] = {};
#pragma unroll
  for (int qt = 0; qt < 2; ++qt)
#pragma unroll
    for (int r = 0; r < 4; ++r) {
      m[qt][r] = -1e30f;
      lsum[qt][r] = 0.f;
    }

  const int nchunk = q0 / 64 + 2;

  short8 kreg[2], vreg[2];
  float4 mreg;

  // prologue: stage chunk 0 into buffer 0
  {
    kreg[0] = *reinterpret_cast<const short8*>(&Kb[(size_t)sr * NHD + scol]);
    kreg[1] = *reinterpret_cast<const short8*>(&Kb[(size_t)(sr + 32) * NHD + scol]);
    vreg[0] = *reinterpret_cast<const short8*>(&Vb[(size_t)sr * NS + scol]);
    vreg[1] = *reinterpret_cast<const short8*>(&Vb[(size_t)(sr + 32) * NS + scol]);
    if (tid < 16) mreg = *reinterpret_cast<const float4*>(&mb[b * NS + tid * 4]);
    *reinterpret_cast<short8*>(&Ks[0][sr][scol]) = kreg[0];
    *reinterpret_cast<short8*>(&Ks[0][sr + 32][scol]) = kreg[1];
    *reinterpret_cast<short8*>(&Vs[0][sr][scol]) = vreg[0];
    *reinterpret_cast<short8*>(&Vs[0][sr + 32][scol]) = vreg[1];
    if (tid < 16) *reinterpret_cast<float4*>(&Mb[0][tid * 4]) = mreg;
  }
  __syncthreads();

  for (int c = 0; c < nchunk; ++c) {
    const int cur = c & 1;
    const int kv0 = c * 64;
    // issue next chunk's global loads early (latency hides under compute)
    if (c + 1 < nchunk) {
      const int nk = kv0 + 64;
      kreg[0] = *reinterpret_cast<const short8*>(&Kb[(size_t)(nk + sr) * NHD + scol]);
      kreg[1] = *reinterpret_cast<const short8*>(&Kb[(size_t)(nk + sr + 32) * NHD + scol]);
      vreg[0] = *reinterpret_cast<const short8*>(&Vb[(size_t)sr * NS + nk + scol]);
      vreg[1] = *reinterpret_cast<const short8*>(&Vb[(size_t)(sr + 32) * NS + nk + scol]);
      if (tid < 16) mreg = *reinterpret_cast<const float4*>(&mb[b * NS + nk + tid * 4]);
    }

    if (kv0 < qw + 32) {  // this wave has unmasked work in the chunk
      // K fragments from LDS
      short8 bk[4][2];
#pragma unroll
      for (int kt = 0; kt < 4; ++kt)
#pragma unroll
        for (int kh = 0; kh < 2; ++kh)
          bk[kt][kh] = *reinterpret_cast<const short8*>(&Ks[cur][kt * 16 + l15][kh * 32 + l4 * 8]);

      f32x4 sc[2][4];
#pragma unroll
      for (int qt = 0; qt < 2; ++qt)
#pragma unroll
        for (int kt = 0; kt < 4; ++kt) {
          f32x4 z = {};
          z = __builtin_amdgcn_mfma_f32_16x16x32_bf16(aq[qt][0], bk[kt][0], z, 0, 0, 0);
          sc[qt][kt] = __builtin_amdgcn_mfma_f32_16x16x32_bf16(aq[qt][1], bk[kt][1], z, 0, 0, 0);
        }

      float bias[4];
#pragma unroll
      for (int kt = 0; kt < 4; ++kt) bias[kt] = Mb[cur][kt * 16 + l15];

#pragma unroll
      for (int qt = 0; qt < 2; ++qt) {
        // scale + padding bias + (diagonal-only) causal mask
#pragma unroll
        for (int kt = 0; kt < 4; ++kt) {
          const bool needc = (kv0 + kt * 16 + 15 > qw + qt * 16);
          const int col = kv0 + kt * 16 + l15;
#pragma unroll
          for (int r = 0; r < 4; ++r) {
            float v = fmaf(sc[qt][kt][r], SM_SCALE, bias[kt]);
            if (needc && col > qw + qt * 16 + l4 * 4 + r) v = -1e30f;
            sc[qt][kt][r] = v;
          }
        }
        // row max (rows live across l15 within l4 groups)
        float pm[4], fac[4];
#pragma unroll
        for (int r = 0; r < 4; ++r) {
          float v = fmaxf(fmaxf(sc[qt][0][r], sc[qt][1][r]), fmaxf(sc[qt][2][r], sc[qt][3][r]));
          v = fmaxf(v, __shfl_xor(v, 1));
          v = fmaxf(v, __shfl_xor(v, 2));
          v = fmaxf(v, __shfl_xor(v, 4));
          v = fmaxf(v, __shfl_xor(v, 8));
          pm[r] = v;
        }
#pragma unroll
        for (int r = 0; r < 4; ++r) {
          float mn = fmaxf(m[qt][r], pm[r]);
          fac[r] = exp2f(m[qt][r] - mn);
          m[qt][r] = mn;
        }
        float rs[4] = {0.f, 0.f, 0.f, 0.f};
#pragma unroll
        for (int kt = 0; kt < 4; ++kt)
#pragma unroll
          for (int r = 0; r < 4; ++r) {
            float p = exp2f(sc[qt][kt][r] - m[qt][r]);
            sc[qt][kt][r] = p;
            rs[r] += p;
          }
#pragma unroll
        for (int r = 0; r < 4; ++r) {
          float v = rs[r];
          v += __shfl_xor(v, 1);
          v += __shfl_xor(v, 2);
          v += __shfl_xor(v, 4);
          v += __shfl_xor(v, 8);
          lsum[qt][r] = lsum[qt][r] * fac[r] + v;
        }
#pragma unroll
        for (int ht = 0; ht < 4; ++ht)
#pragma unroll
          for (int r = 0; r < 4; ++r) o[qt][ht][r] *= fac[r];
        // P (acc layout) -> per-wave LDS slice for PV A-frags
#pragma unroll
        for (int kt = 0; kt < 4; ++kt)
#pragma unroll
          for (int r = 0; r < 4; ++r) {
            bf16 hv = __float2bfloat16(sc[qt][kt][r]);
            Pl[w][qt * 16 + l4 * 4 + r][kt * 16 + l15] = *reinterpret_cast<short*>(&hv);
          }
      }
      // PV from LDS
#pragma unroll
      for (int qt = 0; qt < 2; ++qt) {
        short8 pa[2];
#pragma unroll
        for (int kh = 0; kh < 2; ++kh)
          pa[kh] = *reinterpret_cast<const short8*>(&Pl[w][qt * 16 + l15][kh * 32 + l4 * 8]);
#pragma unroll
        for (int ht = 0; ht < 4; ++ht)
#pragma unroll
          for (int kh = 0; kh < 2; ++kh) {
            short8 bv = *reinterpret_cast<const short8*>(&Vs[cur][ht * 16 + l15][kh * 32 + l4 * 8]);
            o[qt][ht] = __builtin_amdgcn_mfma_f32_16x16x32_bf16(pa[kh], bv, o[qt][ht], 0, 0, 0);
          }
      }
    }

    // write next chunk into the other buffer (waits on the early loads)
    if (c + 1 < nchunk) {
      const int nb_ = (c + 1) & 1;
      *reinterpret_cast<short8*>(&Ks[nb_][sr][scol]) = kreg[0];
      *reinterpret_cast<short8*>(&Ks[nb_][sr + 32][scol]) = kreg[1];
      *reinterpret_cast<short8*>(&Vs[nb_][sr][scol]) = vreg[0];
      *reinterpret_cast<short8*>(&Vs[nb_][sr + 32][scol]) = vreg[1];
      if (tid < 16) *reinterpret_cast<float4*>(&Mb[nb_][tid * 4]) = mreg;
    }
    __syncthreads();
  }

  // epilogue: normalize, write AO bf16 [B,S,D]
  const int h = bh & 15;
#pragma unroll
  for (int qt = 0; qt < 2; ++qt)
#pragma unroll
    for (int ht = 0; ht < 4; ++ht)
#pragma unroll
      for (int r = 0; r < 4; ++r) {
        int srow = qw + qt * 16 + l4 * 4 + r;
        float val = o[qt][ht][r] / lsum[qt][r];
        AO[(size_t)(b * NS + srow) * ND + h * NHD + ht * 16 + l15] = __float2bfloat16(val);
      }
}

extern "C" void kernel_launch(void* const* d_in, const int* in_sizes, int n_in,
                              void* d_out, int out_size, void* d_ws, size_t ws_size,
                              hipStream_t stream) {
  const float* x = (const float*)d_in[0];
  const int* amask = (const int*)d_in[1];
  const float* Wqkv = (const float*)d_in[2];
  const float* Wout = (const float*)d_in[3];
  float* out = (float*)d_out;

  char* p = (char*)d_ws;
  bf16* xb = (bf16*)(p);                      // 8,388,608
  bf16* wqkvb = (bf16*)(p + 8388608);         // 6,291,456 (dead after QKV GEMM)
  bf16* woutb = (bf16*)(p + 14680064);        // 2,097,152
  bf16* qkvb = (bf16*)(p + 16777216);         // 25,165,824
  bf16* Qr = (bf16*)(p + 41943040);           // 8,388,608
  bf16* Kr = (bf16*)(p + 50331648);           // 8,388,608
  bf16* Vt = (bf16*)(p + 58720256);           // 8,388,608 -> 67,108,864 end
  bf16* AO = xb;                              // aliases xb (dead after QKV GEMM)
  float* mbias = (float*)(p + 8388608);       // aliases wqkvb (dead after QKV GEMM), 16 KB

  cast_kernel<<<4096, 256, 0, stream>>>((const float4*)x, xb, (NB * NS * ND) / 4);
  cast_kernel<<<3072, 256, 0, stream>>>((const float4*)Wqkv, wqkvb, (N3D * ND) / 4);
  cast_kernel<<<1024, 256, 0, stream>>>((const float4*)Wout, woutb, (ND * ND) / 4);

  gemm_bt<true><<<dim3(N3D / 64, (NB * NS) / 64), 256, 0, stream>>>(xb, wqkvb, qkvb,
                                                                    NB * NS, N3D, ND);
  rope_kernel<<<(NB * NH * NS * 32) / 256, 256, 0, stream>>>(qkvb, Qr, Kr);
  vtrans_kernel<<<dim3(NS / 64, NB * NH), 256, 0, stream>>>(qkvb, Vt);
  maskbias_kernel<<<16, 256, 0, stream>>>(amask, mbias, NB * NS);
  attn_kernel<<<dim3(NS / 128, NB * NH), 256, 0, stream>>>(Qr, Kr, Vt, mbias, AO);
  gemm_bt<false><<<dim3(ND / 64, (NB * NS) / 64), 256, 0, stream>>>(AO, woutb, out,
                                                                    NB * NS, ND, ND);
}

// Round 3
// 185.054 us; speedup vs baseline: 1.6038x; 1.3015x over previous
//
#include <hip/hip_runtime.h>
#include <hip/hip_bf16.h>
#include <math.h>
#include <stdint.h>

typedef __hip_bfloat16 bf16;
typedef __attribute__((ext_vector_type(8))) short short8;
typedef __attribute__((ext_vector_type(4))) float f32x4;

#define NB 2
#define NS 2048
#define ND 1024
#define NH 16
#define NHD 64
#define N3D 3072

// softmax scale folded into exp2 domain: (1/sqrt(64)) * log2(e)
#define SM_SCALE 0.18033688011112042f

// ---------------- async global->LDS, 16B per lane ----------------
__device__ __forceinline__ void gload16(const bf16* g, void* l) {
  __builtin_amdgcn_global_load_lds(
      (const __attribute__((address_space(1))) uint32_t*)g,
      (__attribute__((address_space(3))) uint32_t*)l, 16, 0, 0);
}

// ---------------- fp32 -> bf16 cast (4-wide) ----------------
__global__ void cast_kernel(const float4* __restrict__ in, bf16* __restrict__ out, int n4) {
  int i = blockIdx.x * blockDim.x + threadIdx.x;
  if (i >= n4) return;
  float4 v = in[i];
  alignas(8) bf16 r[4];
  r[0] = __float2bfloat16(v.x);
  r[1] = __float2bfloat16(v.y);
  r[2] = __float2bfloat16(v.z);
  r[3] = __float2bfloat16(v.w);
  *reinterpret_cast<uint2*>(out + (size_t)i * 4) = *reinterpret_cast<const uint2*>(r);
}

// ---------------- bf16 GEMM (m97 structure): C[M,N] = A[M,K] * B[N,K]^T ----------------
// 128x128 tile, BK=64, 4 waves each computing 64x64 (4x4 frags), global_load_lds staging.
template <bool OUT_BF16>
__global__ __launch_bounds__(256) void gemm_bt(const bf16* __restrict__ A,
                                               const bf16* __restrict__ Bm,
                                               void* __restrict__ Cv,
                                               int M, int N, int K) {
  __shared__ short As[128 * 64];
  __shared__ short Bs[128 * 64];
  const int tid = threadIdx.x;
  const int lane = tid & 63;
  const int w = tid >> 6;
  const int wr = w >> 1, wc = w & 1;
  const int l15 = lane & 15, l4 = lane >> 4;
  const int bn0 = blockIdx.x * 128, bm0 = blockIdx.y * 128;
  const int srow = w * 8 + (lane >> 3);  // staging row within each 32-row group
  const int scol = (lane & 7) * 8;       // staging col (shorts)
  f32x4 acc[4][4] = {};
  for (int k0 = 0; k0 < K; k0 += 64) {
    __syncthreads();  // protect LDS reuse
#pragma unroll
    for (int i = 0; i < 4; ++i) {
      gload16(&A[(size_t)(bm0 + i * 32 + srow) * K + k0 + scol], &As[(i * 32 + w * 8) * 64]);
      gload16(&Bm[(size_t)(bn0 + i * 32 + srow) * K + k0 + scol], &Bs[(i * 32 + w * 8) * 64]);
    }
    __syncthreads();  // drains vmcnt -> tiles visible
#pragma unroll
    for (int kk = 0; kk < 64; kk += 32) {
      short8 am[4], bn[4];
#pragma unroll
      for (int t = 0; t < 4; ++t) {
        am[t] = *reinterpret_cast<const short8*>(&As[(wr * 64 + t * 16 + l15) * 64 + kk + l4 * 8]);
        bn[t] = *reinterpret_cast<const short8*>(&Bs[(wc * 64 + t * 16 + l15) * 64 + kk + l4 * 8]);
      }
#pragma unroll
      for (int m = 0; m < 4; ++m)
#pragma unroll
        for (int n = 0; n < 4; ++n)
          acc[m][n] = __builtin_amdgcn_mfma_f32_16x16x32_bf16(am[m], bn[n], acc[m][n], 0, 0, 0);
    }
  }
#pragma unroll
  for (int m = 0; m < 4; ++m)
#pragma unroll
    for (int n = 0; n < 4; ++n)
#pragma unroll
      for (int r = 0; r < 4; ++r) {
        int row = bm0 + wr * 64 + m * 16 + l4 * 4 + r;
        int col = bn0 + wc * 64 + n * 16 + l15;
        if (OUT_BF16)
          reinterpret_cast<bf16*>(Cv)[(size_t)row * N + col] = __float2bfloat16(acc[m][n][r]);
        else
          reinterpret_cast<float*>(Cv)[(size_t)row * N + col] = acc[m][n][r];
      }
}

// ---------------- RoPE ----------------
__global__ void rope_kernel(const bf16* __restrict__ qkv, bf16* __restrict__ Qr,
                            bf16* __restrict__ Kr) {
  int idx = blockIdx.x * blockDim.x + threadIdx.x;
  int j = idx & 31;
  int s = (idx >> 5) & (NS - 1);
  int h = (idx >> 16) & (NH - 1);
  int b = idx >> 20;
  size_t base = (size_t)(b * NS + s) * N3D + h * NHD;
  float q0 = __bfloat162float(qkv[base + j]);
  float q1 = __bfloat162float(qkv[base + j + 32]);
  float k0 = __bfloat162float(qkv[base + ND + j]);
  float k1 = __bfloat162float(qkv[base + ND + j + 32]);
  float inv = exp2f((float)(2 * j) * (-13.287712379549449f / 64.0f));
  float ang = (float)s * inv;
  float sn, cs;
  sincosf(ang, &sn, &cs);
  size_t o = ((size_t)(b * NH + h) * NS + s) * NHD + j;
  Qr[o] = __float2bfloat16(q0 * cs - q1 * sn);
  Qr[o + 32] = __float2bfloat16(q1 * cs + q0 * sn);
  Kr[o] = __float2bfloat16(k0 * cs - k1 * sn);
  Kr[o + 32] = __float2bfloat16(k1 * cs + k0 * sn);
}

// ---------------- V transpose: qkv v-part -> Vt (bf16 [B,H,HD,S]) ----------------
__global__ __launch_bounds__(256) void vtrans_kernel(const bf16* __restrict__ qkv,
                                                     bf16* __restrict__ Vt) {
  int bh = blockIdx.y;
  int b = bh >> 4, h = bh & 15;
  int s0 = blockIdx.x * 64;
  __shared__ bf16 tile[64][72];
#pragma unroll
  for (int it = 0; it < 16; ++it) {
    int e = it * 256 + threadIdx.x;
    int sr = e >> 6, hd = e & 63;
    tile[sr][hd] = qkv[(size_t)(b * NS + s0 + sr) * N3D + 2 * ND + h * NHD + hd];
  }
  __syncthreads();
#pragma unroll
  for (int it = 0; it < 16; ++it) {
    int e = it * 256 + threadIdx.x;
    int hd = e >> 6, sc = e & 63;
    Vt[((size_t)bh * NHD + hd) * NS + s0 + sc] = tile[sc][hd];
  }
}

// ---------------- attn_mask -> float bias ----------------
__global__ void maskbias_kernel(const int* __restrict__ amask, float* __restrict__ mb, int n) {
  int i = blockIdx.x * blockDim.x + threadIdx.x;
  if (i < n) mb[i] = amask[i] ? 0.f : -1e30f;
}

// ---------------- causal flash attention, sequential-pair balanced ----------------
// 32 q-tiles of 64 rows. Block p: tile (31-p) then tile p => 33 staged chunks/block, const.
// 4 waves x 16 q-rows; KVBLK=64 double-buffered; early-issue prefetch (T14).
__global__ __launch_bounds__(256, 2) void attn_kernel(const bf16* __restrict__ Qr,
                                                      const bf16* __restrict__ Kr,
                                                      const bf16* __restrict__ Vt,
                                                      const float* __restrict__ mb,
                                                      bf16* __restrict__ AO) {
  __shared__ short Ks[2][64][72];
  __shared__ short Vs[2][64][72];
  __shared__ float Mb[2][64];
  __shared__ short Pl[4][16][72];

  const int tid = threadIdx.x;
  const int lane = tid & 63;
  const int w = tid >> 6;
  const int l15 = lane & 15, l4 = lane >> 4;
  const int bh = blockIdx.y, b = bh >> 4, h = bh & 15;
  const int p = blockIdx.x;  // pair index 0..15

  const int n_hi = 32 - p, n_lo = p + 1;  // n_hi + n_lo == 33
  const int q0_hi = 64 * (31 - p), q0_lo = 64 * p;
  const int qwH = q0_hi + w * 16, qwL = q0_lo + w * 16;

  const bf16* Qb = Qr + (size_t)bh * NS * NHD;
  const bf16* Kb = Kr + (size_t)bh * NS * NHD;
  const bf16* Vb = Vt + (size_t)bh * NHD * NS;

  const int sr = (tid * 8) >> 6;
  const int scol = (tid * 8) & 63;

  // Q fragments for both passes (A-frag: row=l15, k = kh*32 + l4*8 + j)
  short8 aqH[2], aqL[2];
#pragma unroll
  for (int kh = 0; kh < 2; ++kh) {
    aqH[kh] = *reinterpret_cast<const short8*>(&Qb[(size_t)(qwH + l15) * NHD + kh * 32 + l4 * 8]);
    aqL[kh] = *reinterpret_cast<const short8*>(&Qb[(size_t)(qwL + l15) * NHD + kh * 32 + l4 * 8]);
  }

  float m[4], lsum[4];
  f32x4 o[4] = {};
#pragma unroll
  for (int r = 0; r < 4; ++r) {
    m[r] = -1e30f;
    lsum[r] = 0.f;
  }

  short8 kreg[2], vreg[2];
  float4 mreg;

  auto prefetch = [&](int kvn) {
    kreg[0] = *reinterpret_cast<const short8*>(&Kb[(size_t)(kvn + sr) * NHD + scol]);
    kreg[1] = *reinterpret_cast<const short8*>(&Kb[(size_t)(kvn + sr + 32) * NHD + scol]);
    vreg[0] = *reinterpret_cast<const short8*>(&Vb[(size_t)sr * NS + kvn + scol]);
    vreg[1] = *reinterpret_cast<const short8*>(&Vb[(size_t)(sr + 32) * NS + kvn + scol]);
    if (tid < 16) mreg = *reinterpret_cast<const float4*>(&mb[b * NS + kvn + tid * 4]);
  };
  auto stage_write = [&](int buf) {
    *reinterpret_cast<short8*>(&Ks[buf][sr][scol]) = kreg[0];
    *reinterpret_cast<short8*>(&Ks[buf][sr + 32][scol]) = kreg[1];
    *reinterpret_cast<short8*>(&Vs[buf][sr][scol]) = vreg[0];
    *reinterpret_cast<short8*>(&Vs[buf][sr + 32][scol]) = vreg[1];
    if (tid < 16) *reinterpret_cast<float4*>(&Mb[buf][tid * 4]) = mreg;
  };

  auto body = [&](const short8 (&aqp)[2], int qw, int kv0, int cur) {
    short8 bk[4][2];
#pragma unroll
    for (int kt = 0; kt < 4; ++kt)
#pragma unroll
      for (int kh = 0; kh < 2; ++kh)
        bk[kt][kh] = *reinterpret_cast<const short8*>(&Ks[cur][kt * 16 + l15][kh * 32 + l4 * 8]);

    f32x4 sc[4];
#pragma unroll
    for (int kt = 0; kt < 4; ++kt) {
      f32x4 z = {};
      z = __builtin_amdgcn_mfma_f32_16x16x32_bf16(aqp[0], bk[kt][0], z, 0, 0, 0);
      sc[kt] = __builtin_amdgcn_mfma_f32_16x16x32_bf16(aqp[1], bk[kt][1], z, 0, 0, 0);
    }

    float bias[4];
#pragma unroll
    for (int kt = 0; kt < 4; ++kt) bias[kt] = Mb[cur][kt * 16 + l15];

    // scale + padding bias + causal (diagonal tiles only)
#pragma unroll
    for (int kt = 0; kt < 4; ++kt) {
      const bool needc = (kv0 + kt * 16 + 15 > qw);
      const int col = kv0 + kt * 16 + l15;
#pragma unroll
      for (int r = 0; r < 4; ++r) {
        float v = fmaf(sc[kt][r], SM_SCALE, bias[kt]);
        if (needc && col > qw + l4 * 4 + r) v = -1e30f;
        sc[kt][r] = v;
      }
    }
    // row max (row = l4*4+r, cols across l15)
    float pm[4];
#pragma unroll
    for (int r = 0; r < 4; ++r) {
      float v = fmaxf(fmaxf(sc[0][r], sc[1][r]), fmaxf(sc[2][r], sc[3][r]));
      v = fmaxf(v, __shfl_xor(v, 1));
      v = fmaxf(v, __shfl_xor(v, 2));
      v = fmaxf(v, __shfl_xor(v, 4));
      v = fmaxf(v, __shfl_xor(v, 8));
      pm[r] = v;
    }
    // T13: skip rescale unless some row's max grew (wave-uniform branch)
    bool need = (pm[0] > m[0]) || (pm[1] > m[1]) || (pm[2] > m[2]) || (pm[3] > m[3]);
    if (__any(need)) {
      float fac[4];
#pragma unroll
      for (int r = 0; r < 4; ++r) {
        float mn = fmaxf(m[r], pm[r]);
        fac[r] = exp2f(m[r] - mn);
        m[r] = mn;
        lsum[r] *= fac[r];
      }
#pragma unroll
      for (int ht = 0; ht < 4; ++ht)
#pragma unroll
        for (int r = 0; r < 4; ++r) o[ht][r] *= fac[r];
    }
    float rs[4] = {0.f, 0.f, 0.f, 0.f};
#pragma unroll
    for (int kt = 0; kt < 4; ++kt)
#pragma unroll
      for (int r = 0; r < 4; ++r) {
        float pv = exp2f(sc[kt][r] - m[r]);
        rs[r] += pv;
        bf16 hv = __float2bfloat16(pv);
        Pl[w][l4 * 4 + r][kt * 16 + l15] = *reinterpret_cast<short*>(&hv);
      }
#pragma unroll
    for (int r = 0; r < 4; ++r) {
      float v = rs[r];
      v += __shfl_xor(v, 1);
      v += __shfl_xor(v, 2);
      v += __shfl_xor(v, 4);
      v += __shfl_xor(v, 8);
      lsum[r] += v;
    }
    // PV
    short8 pa[2];
#pragma unroll
    for (int kh = 0; kh < 2; ++kh)
      pa[kh] = *reinterpret_cast<const short8*>(&Pl[w][l15][kh * 32 + l4 * 8]);
#pragma unroll
    for (int ht = 0; ht < 4; ++ht)
#pragma unroll
      for (int kh = 0; kh < 2; ++kh) {
        short8 bv = *reinterpret_cast<const short8*>(&Vs[cur][ht * 16 + l15][kh * 32 + l4 * 8]);
        o[ht] = __builtin_amdgcn_mfma_f32_16x16x32_bf16(pa[kh], bv, o[ht], 0, 0, 0);
      }
  };

  auto write_out = [&](int qw) {
    float inv[4];
#pragma unroll
    for (int r = 0; r < 4; ++r) inv[r] = 1.0f / lsum[r];
#pragma unroll
    for (int ht = 0; ht < 4; ++ht)
#pragma unroll
      for (int r = 0; r < 4; ++r) {
        int srow = qw + l4 * 4 + r;
        AO[(size_t)(b * NS + srow) * ND + h * NHD + ht * 16 + l15] =
            __float2bfloat16(o[ht][r] * inv[r]);
      }
  };

  // prologue: stage chunk 0 (hi pass) into buffer 0
  prefetch(0);
  stage_write(0);
  __syncthreads();

  int t = 0;
  // ---- pass 0: hi tile ----
  for (int c = 0; c < n_hi; ++c, ++t) {
    const int cur = t & 1;
    const bool pf = (t + 1 < 33);
    if (pf) prefetch((c + 1 < n_hi) ? (c + 1) * 64 : 0);
    if (c * 64 < qwH + 16) body(aqH, qwH, c * 64, cur);
    if (pf) stage_write(cur ^ 1);
    __syncthreads();
  }
  write_out(qwH);
#pragma unroll
  for (int r = 0; r < 4; ++r) {
    m[r] = -1e30f;
    lsum[r] = 0.f;
  }
#pragma unroll
  for (int ht = 0; ht < 4; ++ht) o[ht] = f32x4{};

  // ---- pass 1: lo tile ----
  for (int c = 0; c < n_lo; ++c, ++t) {
    const int cur = t & 1;
    const bool pf = (t + 1 < 33);
    if (pf) prefetch((c + 1) * 64);
    if (c * 64 < qwL + 16) body(aqL, qwL, c * 64, cur);
    if (pf) stage_write(cur ^ 1);
    __syncthreads();
  }
  write_out(qwL);
}

extern "C" void kernel_launch(void* const* d_in, const int* in_sizes, int n_in,
                              void* d_out, int out_size, void* d_ws, size_t ws_size,
                              hipStream_t stream) {
  const float* x = (const float*)d_in[0];
  const int* amask = (const int*)d_in[1];
  const float* Wqkv = (const float*)d_in[2];
  const float* Wout = (const float*)d_in[3];
  float* out = (float*)d_out;

  char* p = (char*)d_ws;
  bf16* xb = (bf16*)(p);                // 8,388,608
  bf16* wqkvb = (bf16*)(p + 8388608);   // 6,291,456 (dead after QKV GEMM)
  bf16* woutb = (bf16*)(p + 14680064);  // 2,097,152
  bf16* qkvb = (bf16*)(p + 16777216);   // 25,165,824
  bf16* Qr = (bf16*)(p + 41943040);     // 8,388,608
  bf16* Kr = (bf16*)(p + 50331648);     // 8,388,608
  bf16* Vt = (bf16*)(p + 58720256);     // 8,388,608 -> 67,108,864 end
  bf16* AO = xb;                        // aliases xb (dead after QKV GEMM)
  float* mbias = (float*)(p + 8388608); // aliases wqkvb (dead after QKV GEMM)

  cast_kernel<<<4096, 256, 0, stream>>>((const float4*)x, xb, (NB * NS * ND) / 4);
  cast_kernel<<<3072, 256, 0, stream>>>((const float4*)Wqkv, wqkvb, (N3D * ND) / 4);
  cast_kernel<<<1024, 256, 0, stream>>>((const float4*)Wout, woutb, (ND * ND) / 4);

  gemm_bt<true><<<dim3(N3D / 128, (NB * NS) / 128), 256, 0, stream>>>(xb, wqkvb, qkvb,
                                                                      NB * NS, N3D, ND);
  rope_kernel<<<(NB * NH * NS * 32) / 256, 256, 0, stream>>>(qkvb, Qr, Kr);
  vtrans_kernel<<<dim3(NS / 64, NB * NH), 256, 0, stream>>>(qkvb, Vt);
  maskbias_kernel<<<16, 256, 0, stream>>>(amask, mbias, NB * NS);
  attn_kernel<<<dim3(16, NB * NH), 256, 0, stream>>>(Qr, Kr, Vt, mbias, AO);
  gemm_bt<false><<<dim3(ND / 128, (NB * NS) / 128), 256, 0, stream>>>(AO, woutb, out,
                                                                      NB * NS, ND, ND);
}

// Round 4
// 160.091 us; speedup vs baseline: 1.8539x; 1.1559x over previous
//
#include <hip/hip_runtime.h>
#include <hip/hip_bf16.h>
#include <math.h>
#include <stdint.h>

typedef __hip_bfloat16 bf16;
typedef __attribute__((ext_vector_type(8))) short short8;
typedef __attribute__((ext_vector_type(4))) float f32x4;
typedef __attribute__((ext_vector_type(16))) float f32x16;

#define NB 2
#define NS 2048
#define ND 1024
#define NH 16
#define NHD 64
#define N3D 3072

// softmax scale folded into exp2 domain: (1/sqrt(64)) * log2(e)
#define SM_SCALE 0.18033688011112042f

// ---------------- async global->LDS, 16B per lane ----------------
__device__ __forceinline__ void gload16(const bf16* g, void* l) {
  __builtin_amdgcn_global_load_lds(
      (const __attribute__((address_space(1))) uint32_t*)g,
      (__attribute__((address_space(3))) uint32_t*)l, 16, 0, 0);
}

// ---------------- fp32 -> bf16 cast (4-wide) ----------------
__global__ void cast_kernel(const float4* __restrict__ in, bf16* __restrict__ out, int n4) {
  int i = blockIdx.x * blockDim.x + threadIdx.x;
  if (i >= n4) return;
  float4 v = in[i];
  alignas(8) bf16 r[4];
  r[0] = __float2bfloat16(v.x);
  r[1] = __float2bfloat16(v.y);
  r[2] = __float2bfloat16(v.z);
  r[3] = __float2bfloat16(v.w);
  *reinterpret_cast<uint2*>(out + (size_t)i * 4) = *reinterpret_cast<const uint2*>(r);
}

// ---------------- bf16 GEMM (m97 structure): C[M,N] = A[M,K] * B[N,K]^T ----------------
template <bool OUT_BF16>
__global__ __launch_bounds__(256) void gemm_bt(const bf16* __restrict__ A,
                                               const bf16* __restrict__ Bm,
                                               void* __restrict__ Cv,
                                               int M, int N, int K) {
  __shared__ short As[128 * 64];
  __shared__ short Bs[128 * 64];
  const int tid = threadIdx.x;
  const int lane = tid & 63;
  const int w = tid >> 6;
  const int wr = w >> 1, wc = w & 1;
  const int l15 = lane & 15, l4 = lane >> 4;
  const int bn0 = blockIdx.x * 128, bm0 = blockIdx.y * 128;
  const int srow = w * 8 + (lane >> 3);
  const int scol = (lane & 7) * 8;
  f32x4 acc[4][4] = {};
  for (int k0 = 0; k0 < K; k0 += 64) {
    __syncthreads();
#pragma unroll
    for (int i = 0; i < 4; ++i) {
      gload16(&A[(size_t)(bm0 + i * 32 + srow) * K + k0 + scol], &As[(i * 32 + w * 8) * 64]);
      gload16(&Bm[(size_t)(bn0 + i * 32 + srow) * K + k0 + scol], &Bs[(i * 32 + w * 8) * 64]);
    }
    __syncthreads();
#pragma unroll
    for (int kk = 0; kk < 64; kk += 32) {
      short8 am[4], bn[4];
#pragma unroll
      for (int t = 0; t < 4; ++t) {
        am[t] = *reinterpret_cast<const short8*>(&As[(wr * 64 + t * 16 + l15) * 64 + kk + l4 * 8]);
        bn[t] = *reinterpret_cast<const short8*>(&Bs[(wc * 64 + t * 16 + l15) * 64 + kk + l4 * 8]);
      }
#pragma unroll
      for (int m = 0; m < 4; ++m)
#pragma unroll
        for (int n = 0; n < 4; ++n)
          acc[m][n] = __builtin_amdgcn_mfma_f32_16x16x32_bf16(am[m], bn[n], acc[m][n], 0, 0, 0);
    }
  }
#pragma unroll
  for (int m = 0; m < 4; ++m)
#pragma unroll
    for (int n = 0; n < 4; ++n)
#pragma unroll
      for (int r = 0; r < 4; ++r) {
        int row = bm0 + wr * 64 + m * 16 + l4 * 4 + r;
        int col = bn0 + wc * 64 + n * 16 + l15;
        if (OUT_BF16)
          reinterpret_cast<bf16*>(Cv)[(size_t)row * N + col] = __float2bfloat16(acc[m][n][r]);
        else
          reinterpret_cast<float*>(Cv)[(size_t)row * N + col] = acc[m][n][r];
      }
}

// ---------------- RoPE ----------------
__global__ void rope_kernel(const bf16* __restrict__ qkv, bf16* __restrict__ Qr,
                            bf16* __restrict__ Kr) {
  int idx = blockIdx.x * blockDim.x + threadIdx.x;
  int j = idx & 31;
  int s = (idx >> 5) & (NS - 1);
  int h = (idx >> 16) & (NH - 1);
  int b = idx >> 20;
  size_t base = (size_t)(b * NS + s) * N3D + h * NHD;
  float q0 = __bfloat162float(qkv[base + j]);
  float q1 = __bfloat162float(qkv[base + j + 32]);
  float k0 = __bfloat162float(qkv[base + ND + j]);
  float k1 = __bfloat162float(qkv[base + ND + j + 32]);
  float inv = exp2f((float)(2 * j) * (-13.287712379549449f / 64.0f));
  float ang = (float)s * inv;
  float sn, cs;
  sincosf(ang, &sn, &cs);
  size_t o = ((size_t)(b * NH + h) * NS + s) * NHD + j;
  Qr[o] = __float2bfloat16(q0 * cs - q1 * sn);
  Qr[o + 32] = __float2bfloat16(q1 * cs + q0 * sn);
  Kr[o] = __float2bfloat16(k0 * cs - k1 * sn);
  Kr[o + 32] = __float2bfloat16(k1 * cs + k0 * sn);
}

// ---------------- V transpose: qkv v-part -> Vt (bf16 [B,H,HD,S]) ----------------
__global__ __launch_bounds__(256) void vtrans_kernel(const bf16* __restrict__ qkv,
                                                     bf16* __restrict__ Vt) {
  int bh = blockIdx.y;
  int b = bh >> 4, h = bh & 15;
  int s0 = blockIdx.x * 64;
  __shared__ bf16 tile[64][72];
#pragma unroll
  for (int it = 0; it < 16; ++it) {
    int e = it * 256 + threadIdx.x;
    int sr = e >> 6, hd = e & 63;
    tile[sr][hd] = qkv[(size_t)(b * NS + s0 + sr) * N3D + 2 * ND + h * NHD + hd];
  }
  __syncthreads();
#pragma unroll
  for (int it = 0; it < 16; ++it) {
    int e = it * 256 + threadIdx.x;
    int hd = e >> 6, sc = e & 63;
    Vt[((size_t)bh * NHD + hd) * NS + s0 + sc] = tile[sc][hd];
  }
}

// ---------------- attn_mask -> float bias ----------------
__global__ void maskbias_kernel(const int* __restrict__ amask, float* __restrict__ mb, int n) {
  int i = blockIdx.x * blockDim.x + threadIdx.x;
  if (i < n) mb[i] = amask[i] ? 0.f : -1e30f;
}

// ---------------- causal flash attention: 32x32 swapped-QK^T, in-register softmax ----------
// 4 waves/block, 32 q-rows/wave (128/block). KVBLK=64, K/V double-buffered in LDS with
// T2 XOR swizzle. P stays in registers (T12 cvt_pk + permlane32_swap). T13 defer-max.
// Grid: 512 linear blocks, XCD-grouped (4 bh per XCD), long tiles first, long+short paired.
__global__ __launch_bounds__(256, 2) void attn_kernel(const bf16* __restrict__ Qr,
                                                      const bf16* __restrict__ Kr,
                                                      const bf16* __restrict__ Vt,
                                                      const float* __restrict__ mb,
                                                      bf16* __restrict__ AO) {
  __shared__ short Ks[2][64 * 64];
  __shared__ short Vs[2][64 * 64];
  __shared__ float Mb[2][64];

  const int tid = threadIdx.x;
  const int lane = tid & 63;
  const int w = tid >> 6;
  const int q = lane & 31;  // q-col for QK / hd-col for PV
  const int hi = lane >> 5;

  // block mapping: xcd = lin&7 -> bh group; long tiles (k<32) first, short after
  const int lin = blockIdx.x;
  const int xcd = lin & 7;
  const int k = lin >> 3;  // 0..63 within XCD
  const int bh = xcd * 4 + (k & 3);
  const int kk = k >> 2;  // 0..15
  const int tile = (k < 32) ? (15 - kk) : (kk - 8);
  const int b = bh >> 4, h = bh & 15;
  const int qw = tile * 128 + w * 32;
  const int nc = 2 * tile + 2;

  const bf16* Qb = Qr + (size_t)bh * NS * NHD;
  const bf16* Kb = Kr + (size_t)bh * NS * NHD;
  const bf16* Vb = Vt + (size_t)bh * NHD * NS;

  // staging: thread covers 32B of K row and 32B of V row
  const int srow = tid >> 2;            // 0..63 (kv for K, hd for V)
  const int sc0 = (tid & 3) * 16;       // shorts
  const int swz = (srow & 7) << 3;      // XOR swizzle (shorts)

  // Q B-frags (col=q, k = s*16 + hi*8 + j)
  short8 Qf[4];
#pragma unroll
  for (int s = 0; s < 4; ++s)
    Qf[s] = *reinterpret_cast<const short8*>(&Qb[(size_t)(qw + q) * NHD + s * 16 + hi * 8]);

  f32x16 o0 = {}, o1 = {};
  float mx = -1e30f, lsum = 0.f;

  short8 kreg[2], vreg[2];
  float4 mreg;
  auto prefetch = [&](int kv0) {
    kreg[0] = *reinterpret_cast<const short8*>(&Kb[(size_t)(kv0 + srow) * NHD + sc0]);
    kreg[1] = *reinterpret_cast<const short8*>(&Kb[(size_t)(kv0 + srow) * NHD + sc0 + 8]);
    vreg[0] = *reinterpret_cast<const short8*>(&Vb[(size_t)srow * NS + kv0 + sc0]);
    vreg[1] = *reinterpret_cast<const short8*>(&Vb[(size_t)srow * NS + kv0 + sc0 + 8]);
    if (tid < 16) mreg = *reinterpret_cast<const float4*>(&mb[b * NS + kv0 + tid * 4]);
  };
  auto stage = [&](int buf) {
    *reinterpret_cast<short8*>(&Ks[buf][srow * 64 + (sc0 ^ swz)]) = kreg[0];
    *reinterpret_cast<short8*>(&Ks[buf][srow * 64 + ((sc0 + 8) ^ swz)]) = kreg[1];
    *reinterpret_cast<short8*>(&Vs[buf][srow * 64 + (sc0 ^ swz)]) = vreg[0];
    *reinterpret_cast<short8*>(&Vs[buf][srow * 64 + ((sc0 + 8) ^ swz)]) = vreg[1];
    if (tid < 16) *reinterpret_cast<float4*>(&Mb[buf][tid * 4]) = mreg;
  };

  prefetch(0);
  stage(0);
  __syncthreads();

  const int rsw = (q & 7) << 3;  // read-side swizzle for rows q and q+32 (same &7)

  for (int c = 0; c < nc; ++c) {
    const int cur = c & 1;
    const int kv0 = c * 64;
    if (c + 1 < nc) prefetch((c + 1) * 64);

    if (kv0 < qw + 32) {
      // ---- QK^T swapped: acc_t[r] = S[q][kv0 + 32t + crow(r,hi)] ----
      f32x16 a0 = {}, a1 = {};
#pragma unroll
      for (int s = 0; s < 4; ++s) {
        short8 kf0 = *reinterpret_cast<const short8*>(
            &Ks[cur][q * 64 + ((s * 16 + hi * 8) ^ rsw)]);
        short8 kf1 = *reinterpret_cast<const short8*>(
            &Ks[cur][(32 + q) * 64 + ((s * 16 + hi * 8) ^ rsw)]);
        a0 = __builtin_amdgcn_mfma_f32_32x32x16_bf16(kf0, Qf[s], a0, 0, 0, 0);
        a1 = __builtin_amdgcn_mfma_f32_32x32x16_bf16(kf1, Qf[s], a1, 0, 0, 0);
      }

      // ---- scale + padding bias + causal ----
      float4 bv[2][4];
#pragma unroll
      for (int t = 0; t < 2; ++t)
#pragma unroll
        for (int g = 0; g < 4; ++g)
          bv[t][g] = *reinterpret_cast<const float4*>(&Mb[cur][t * 32 + g * 8 + hi * 4]);
      const int qg = qw + q;
#pragma unroll
      for (int t = 0; t < 2; ++t) {
        f32x16& a = t ? a1 : a0;
        const bool needc = (kv0 + t * 32 + 31 > qw);
#pragma unroll
        for (int r = 0; r < 16; ++r) {
          float v = fmaf(a[r], SM_SCALE, ((const float*)&bv[t][r >> 2])[r & 3]);
          if (needc) {
            int kvg = kv0 + t * 32 + (r & 3) + 8 * (r >> 2) + 4 * hi;
            if (kvg > qg) v = -1e30f;
          }
          a[r] = v;
        }
      }

      // ---- row max: in-lane 32 + cross-half ----
      float cm = a0[0];
#pragma unroll
      for (int r = 1; r < 16; ++r) cm = fmaxf(cm, a0[r]);
#pragma unroll
      for (int r = 0; r < 16; ++r) cm = fmaxf(cm, a1[r]);
      float pm = fmaxf(cm, __shfl_xor(cm, 32));

      // ---- T13 defer-max rescale ----
      if (!__all(pm <= mx + 8.f)) {
        float mn = fmaxf(mx, pm);
        float fac = __builtin_amdgcn_exp2f(mx - mn);
        mx = mn;
        lsum *= fac;
#pragma unroll
        for (int r = 0; r < 16; ++r) {
          float fq = __shfl(fac, (r & 3) + 8 * (r >> 2) + 4 * hi);
          o0[r] *= fq;
          o1[r] *= fq;
        }
      }

      // ---- exp2, row-sum, pack P -> PV A-frags (in-register) ----
      float rs = 0.f;
      short8 pa[4];
#pragma unroll
      for (int t = 0; t < 2; ++t) {
        f32x16& a = t ? a1 : a0;
#pragma unroll
        for (int r = 0; r < 16; ++r) {
          float e = __builtin_amdgcn_exp2f(a[r] - mx);
          a[r] = e;
          rs += e;
        }
#pragma unroll
        for (int g = 0; g < 2; ++g) {
          union { unsigned int u; __hip_bfloat162 h2; } X, X2, Y, Y2;
          X.h2 = __float22bfloat162_rn(float2{a[g * 8 + 0], a[g * 8 + 1]});
          X2.h2 = __float22bfloat162_rn(float2{a[g * 8 + 2], a[g * 8 + 3]});
          Y.h2 = __float22bfloat162_rn(float2{a[g * 8 + 4], a[g * 8 + 5]});
          Y2.h2 = __float22bfloat162_rn(float2{a[g * 8 + 6], a[g * 8 + 7]});
          asm volatile("v_permlane32_swap_b32 %0, %1" : "+v"(X.u), "+v"(Y.u));
          asm volatile("v_permlane32_swap_b32 %0, %1" : "+v"(X2.u), "+v"(Y2.u));
          union { unsigned int u[4]; short8 s; } P;
          P.u[0] = X.u;
          P.u[1] = X2.u;
          P.u[2] = Y.u;
          P.u[3] = Y2.u;
          pa[t * 2 + g] = P.s;
        }
      }
      lsum += rs + __shfl_xor(rs, 32);

      // ---- PV: O[q'][hd] += P * V ----
#pragma unroll
      for (int ks = 0; ks < 4; ++ks) {
        const int vcol = (ks * 16 + hi * 8) ^ rsw;
        short8 vf0 = *reinterpret_cast<const short8*>(&Vs[cur][q * 64 + vcol]);
        short8 vf1 = *reinterpret_cast<const short8*>(&Vs[cur][(32 + q) * 64 + vcol]);
        o0 = __builtin_amdgcn_mfma_f32_32x32x16_bf16(pa[ks], vf0, o0, 0, 0, 0);
        o1 = __builtin_amdgcn_mfma_f32_32x32x16_bf16(pa[ks], vf1, o1, 0, 0, 0);
      }
    }

    if (c + 1 < nc) stage(cur ^ 1);
    __syncthreads();
  }

  // ---- epilogue: normalize + write AO [B,S,D] ----
  float inv = 1.0f / lsum;
#pragma unroll
  for (int r = 0; r < 16; ++r) {
    const int crow = (r & 3) + 8 * (r >> 2) + 4 * hi;
    float iq = __shfl(inv, crow);
    size_t base = (size_t)(b * NS + qw + crow) * ND + h * NHD;
    AO[base + q] = __float2bfloat16(o0[r] * iq);
    AO[base + 32 + q] = __float2bfloat16(o1[r] * iq);
  }
}

extern "C" void kernel_launch(void* const* d_in, const int* in_sizes, int n_in,
                              void* d_out, int out_size, void* d_ws, size_t ws_size,
                              hipStream_t stream) {
  const float* x = (const float*)d_in[0];
  const int* amask = (const int*)d_in[1];
  const float* Wqkv = (const float*)d_in[2];
  const float* Wout = (const float*)d_in[3];
  float* out = (float*)d_out;

  char* p = (char*)d_ws;
  bf16* xb = (bf16*)(p);                 // 8,388,608
  bf16* wqkvb = (bf16*)(p + 8388608);    // 6,291,456 (dead after QKV GEMM)
  bf16* woutb = (bf16*)(p + 14680064);   // 2,097,152
  bf16* qkvb = (bf16*)(p + 16777216);    // 25,165,824
  bf16* Qr = (bf16*)(p + 41943040);      // 8,388,608
  bf16* Kr = (bf16*)(p + 50331648);      // 8,388,608
  bf16* Vt = (bf16*)(p + 58720256);      // 8,388,608 -> 67,108,864 end
  bf16* AO = xb;                         // aliases xb (dead after QKV GEMM)
  float* mbias = (float*)(p + 8388608);  // aliases wqkvb (dead after QKV GEMM)

  cast_kernel<<<4096, 256, 0, stream>>>((const float4*)x, xb, (NB * NS * ND) / 4);
  cast_kernel<<<3072, 256, 0, stream>>>((const float4*)Wqkv, wqkvb, (N3D * ND) / 4);
  cast_kernel<<<1024, 256, 0, stream>>>((const float4*)Wout, woutb, (ND * ND) / 4);

  gemm_bt<true><<<dim3(N3D / 128, (NB * NS) / 128), 256, 0, stream>>>(xb, wqkvb, qkvb,
                                                                      NB * NS, N3D, ND);
  rope_kernel<<<(NB * NH * NS * 32) / 256, 256, 0, stream>>>(qkvb, Qr, Kr);
  vtrans_kernel<<<dim3(NS / 64, NB * NH), 256, 0, stream>>>(qkvb, Vt);
  maskbias_kernel<<<16, 256, 0, stream>>>(amask, mbias, NB * NS);
  attn_kernel<<<512, 256, 0, stream>>>(Qr, Kr, Vt, mbias, AO);
  gemm_bt<false><<<dim3(ND / 128, (NB * NS) / 128), 256, 0, stream>>>(AO, woutb, out,
                                                                      NB * NS, ND, ND);
}